// Round 7
// baseline (115.945 us; speedup 1.0000x reference)
//
#include <hip/hip_runtime.h>

#define B_  16
#define TQ  128
#define TK  256
#define DIN 64
#define H_  256
#define DV  256
#define HT  8          // h-cols per proj_k block
#define QT  2          // q-rows per attn block
#define NW  8          // waves per attn block (512 threads)
#define NEG -1000000.0f

// tanh(x) = 1 - 2*rcp(1 + exp2(SCALE*x)), SCALE = 2*log2(e)
#define SCALE  2.8853900817779268f
#define LOG2E  1.4426950408889634f

__device__ inline float fast_exp2(float x) { return __builtin_amdgcn_exp2f(x); }
__device__ inline float fast_rcp(float x)  { return __builtin_amdgcn_rcpf(x); }

// ---------------- Kernel B: kpT[b,h,k] = SCALE * sum_d keys[b,k,d]*wk[d,h] ----------------
// grid = B*(H/HT) = 512 blocks, 256 threads (t = k). Skips k >= ceil64(vl): those
// entries stay 0xAA-poisoned (= -3.0e-13f, finite) and are masked to NEG downstream.
__global__ __launch_bounds__(256) void proj_k_kernel(
    const float* __restrict__ keys, const float* __restrict__ wk,
    float* __restrict__ kpT, const int* __restrict__ valid_lens)
{
    int b  = blockIdx.x >> 5;            // H_/HT == 32
    int h0 = (blockIdx.x & 31) * HT;
    int t  = threadIdx.x;                // k index
    int vlC = (valid_lens[b] + 63) & ~63;
    if (t >= vlC) return;                // wave-uniform exit
    const float* krow = keys + (b * TK + t) * DIN;
    float acc[HT];
    #pragma unroll
    for (int hh = 0; hh < HT; ++hh) acc[hh] = 0.f;
    #pragma unroll 4
    for (int d = 0; d < DIN; ++d) {
        float kv = krow[d];
        #pragma unroll
        for (int hh = 0; hh < HT; ++hh)
            acc[hh] = fmaf(kv, wk[d * H_ + h0 + hh], acc[hh]);
    }
    #pragma unroll
    for (int hh = 0; hh < HT; ++hh)
        kpT[(b * H_ + h0 + hh) * TK + t] = acc[hh] * SCALE;
}

__device__ inline float waveMax(float v) {
    #pragma unroll
    for (int off = 32; off > 0; off >>= 1) v = fmaxf(v, __shfl_xor(v, off, 64));
    return v;
}
__device__ inline float waveSum(float v) {
    #pragma unroll
    for (int off = 32; off > 0; off >>= 1) v += __shfl_xor(v, off, 64);
    return v;
}

// ---------------- Kernel C: fused q-proj + scores(2 rows) + softmax + attn@V ----------------
// grid = B*(TQ/QT) = 1024 blocks, 512 threads, __launch_bounds__(512,8):
// 4 blocks/CU * 8 waves = 32 waves/CU (HW cap) for max latency hiding.
// Phase 1: wave w owns h in [32w,32w+32); lane l covers k=4l..4l+3 via one float4
// load feeding 8 sigmoid terms (~180 issue-cyc per load). Inner loop uses
// score = W - 2*sum(wv*r) with r = rcp(1+exp2(u)) -> 5 instr per element.
__global__ __launch_bounds__(512, 8) void attn_kernel(
    const float* __restrict__ queries, const float* __restrict__ wq,
    const float* __restrict__ kpT,
    const float* __restrict__ values, const int* __restrict__ valid_lens,
    const float* __restrict__ wv, float* __restrict__ out)
{
    __shared__ float4 qw4[H_];             // (q0*S, q1*S, wv_h, -): one b128 broadcast/iter
    __shared__ float  scoreP[NW][QT][TK];  // 16 KB partial sums of wv*r; [0] reused ph3
    __shared__ float2 attnT[TK];           // attn weights k-major (b64 broadcast ph3)

    // XCD swizzle: 2 batches per XCD slot -> ~1.25 MB hot set per XCD L2.
    int bx  = blockIdx.x;
    int xcd = bx & 7;
    int i   = bx >> 3;                     // 0..127
    int b   = xcd + 8 * (i & 1);
    int q0  = (i >> 1) * QT;               // 0,2,...,126
    int t   = threadIdx.x;                 // 0..511
    int w   = t >> 6, l = t & 63;
    int vl  = valid_lens[b];

    // ---- phase 0: project the 2 query rows (first 256 threads, t = h) ----
    if (t < 256) {
        const float* qbase = queries + (b * TQ + q0) * DIN;   // uniform -> s_load
        float a0 = 0.f, a1 = 0.f;
        #pragma unroll
        for (int d = 0; d < DIN; ++d) {
            float ww = wq[d * H_ + t];                // coalesced, L2-hot
            a0 = fmaf(qbase[d],       ww, a0);
            a1 = fmaf(qbase[DIN + d], ww, a1);
        }
        qw4[t] = make_float4(a0 * SCALE, a1 * SCALE, wv[t], 0.f);
    }
    __syncthreads();

    // ---- phase 1: wave w covers h in [32w,32w+32); lane l covers k=4l..4l+3 ----
    // accumulate sum(wv * r); tanh fold happens in phase 2 (score = W - 2*sum)
    {
        const float4* kp4 = (const float4*)(kpT + (size_t)b * H_ * TK);
        float4 s0 = {0,0,0,0}, s1 = {0,0,0,0};
        int h0 = w * (H_ / NW);
        #pragma unroll 4
        for (int hh = 0; hh < H_ / NW; ++hh) {
            int h = h0 + hh;
            float4 kv = kp4[h * (TK / 4) + l];    // coalesced 1 KB/wave, L2-hot
            float4 qv = qw4[h];                   // broadcast b128
            float r0x = fast_rcp(fast_exp2(qv.x + kv.x) + 1.f);
            float r0y = fast_rcp(fast_exp2(qv.x + kv.y) + 1.f);
            float r0z = fast_rcp(fast_exp2(qv.x + kv.z) + 1.f);
            float r0w = fast_rcp(fast_exp2(qv.x + kv.w) + 1.f);
            s0.x = fmaf(qv.z, r0x, s0.x);
            s0.y = fmaf(qv.z, r0y, s0.y);
            s0.z = fmaf(qv.z, r0z, s0.z);
            s0.w = fmaf(qv.z, r0w, s0.w);
            float r1x = fast_rcp(fast_exp2(qv.y + kv.x) + 1.f);
            float r1y = fast_rcp(fast_exp2(qv.y + kv.y) + 1.f);
            float r1z = fast_rcp(fast_exp2(qv.y + kv.z) + 1.f);
            float r1w = fast_rcp(fast_exp2(qv.y + kv.w) + 1.f);
            s1.x = fmaf(qv.z, r1x, s1.x);
            s1.y = fmaf(qv.z, r1y, s1.y);
            s1.z = fmaf(qv.z, r1z, s1.z);
            s1.w = fmaf(qv.z, r1w, s1.w);
        }
        ((float4*)&scoreP[w][0][0])[l] = s0;      // b128 stores
        ((float4*)&scoreP[w][1][0])[l] = s1;
    }
    __syncthreads();

    // ---- phase 2: wave r (r<QT) softmaxes row q0+r; lane covers k=4l..4l+3 ----
    if (t < 64 * QT) {
        int r = w;
        // W = sum_h wv_h (full 256): 4 strided reads + wave reduce, once per row-wave
        float W = waveSum(qw4[l].z + qw4[l + 64].z + qw4[l + 128].z + qw4[l + 192].z);
        float4 v = {0, 0, 0, 0};
        #pragma unroll
        for (int s = 0; s < NW; ++s) {
            float4 ps = ((const float4*)&scoreP[s][r][0])[l];
            v.x += ps.x; v.y += ps.y; v.z += ps.z; v.w += ps.w;
        }
        int k0 = 4 * l;
        v.x = (k0     < vl) ? fmaf(-2.f, v.x, W) : NEG;   // score = W - 2*sum(wv*r)
        v.y = (k0 + 1 < vl) ? fmaf(-2.f, v.y, W) : NEG;
        v.z = (k0 + 2 < vl) ? fmaf(-2.f, v.z, W) : NEG;
        v.w = (k0 + 3 < vl) ? fmaf(-2.f, v.w, W) : NEG;
        float m  = waveMax(fmaxf(fmaxf(v.x, v.y), fmaxf(v.z, v.w)));
        // vl>0: masked p underflows to exactly 0 (matches ref). vl==0: uniform.
        float p0 = fast_exp2((v.x - m) * LOG2E);
        float p1 = fast_exp2((v.y - m) * LOG2E);
        float p2 = fast_exp2((v.z - m) * LOG2E);
        float p3 = fast_exp2((v.w - m) * LOG2E);
        float dr = fast_rcp(waveSum(p0 + p1 + p2 + p3));
        ((float*)&attnT[k0    ])[r] = p0 * dr;
        ((float*)&attnT[k0 + 1])[r] = p1 * dr;
        ((float*)&attnT[k0 + 2])[r] = p2 * dr;
        ((float*)&attnT[k0 + 3])[r] = p3 * dr;
    }
    __syncthreads();

    // ---- phase 3: half-block splits k-range, clipped to vl (weights for k>=vl are 0) ----
    {
        int half = t >> 8, v = t & 255;
        int kLim = (vl == 0) ? TK : vl;        // vl==0: uniform weights over all k
        int kBeg = half * (TK / 2);
        int kEnd = min(kBeg + TK / 2, kLim);   // half1 empty when kLim<=128
        const float* vcol = values + (size_t)b * TK * DV + v;
        float o0 = 0.f, o1 = 0.f;
        #pragma unroll 4
        for (int k = kBeg; k < kEnd; ++k) {
            float  vv = vcol[k * DV];          // coalesced over v
            float2 a  = attnT[k];              // broadcast b64
            o0 = fmaf(a.x, vv, o0);
            o1 = fmaf(a.y, vv, o1);
        }
        if (half == 1) {                       // stash partials (reuse scoreP[0])
            scoreP[0][0][v] = o0;
            scoreP[0][1][v] = o1;
        }
        __syncthreads();
        if (half == 0) {
            float* orow = out + (size_t)(b * TQ + q0) * DV + v;
            orow[0]  = o0 + scoreP[0][0][v];
            orow[DV] = o1 + scoreP[0][1][v];
        }
    }
}

extern "C" void kernel_launch(void* const* d_in, const int* in_sizes, int n_in,
                              void* d_out, int out_size, void* d_ws, size_t ws_size,
                              hipStream_t stream) {
    const float* queries    = (const float*)d_in[0];
    const float* keys       = (const float*)d_in[1];
    const float* values     = (const float*)d_in[2];
    const int*   valid_lens = (const int*)  d_in[3];
    const float* wq         = (const float*)d_in[4];
    const float* wk         = (const float*)d_in[5];
    const float* wv         = (const float*)d_in[6];
    float* out = (float*)d_out;

    float* kpT = (float*)d_ws;   // [B,H,TK] = 4 MiB

    proj_k_kernel<<<B_ * (H_ / HT), 256, 0, stream>>>(keys, wk, kpT, valid_lens);
    attn_kernel<<<B_ * (TQ / QT), 512, 0, stream>>>(queries, wq, kpT, values,
                                                    valid_lens, wv, out);
}

// Round 8
// 112.259 us; speedup vs baseline: 1.0328x; 1.0328x over previous
//
#include <hip/hip_runtime.h>

#define B_  16
#define TQ  128
#define TK  256
#define DIN 64
#define H_  256
#define DV  256
#define HT  8          // h-cols per proj_k block
#define QT  4          // q-rows per attn block
#define NW  8          // waves per attn block (512 threads)
#define NEG -1000000.0f

// tanh(x) = 1 - 2*rcp(1 + exp2(SCALE*x)), SCALE = 2*log2(e)
#define SCALE  2.8853900817779268f
#define LOG2E  1.4426950408889634f

__device__ inline float fast_exp2(float x) { return __builtin_amdgcn_exp2f(x); }
__device__ inline float fast_rcp(float x)  { return __builtin_amdgcn_rcpf(x); }

// ---------------- Kernel B: kpT[b,h,k] = SCALE * sum_d keys[b,k,d]*wk[d,h] ----------------
// grid = B*(H/HT) = 512 blocks, 256 threads (t = k). float4 keys loads (4x fewer VMEM).
// Skips k >= ceil64(vl): those entries stay poisoned and are masked to NEG downstream.
__global__ __launch_bounds__(256) void proj_k_kernel(
    const float* __restrict__ keys, const float* __restrict__ wk,
    float* __restrict__ kpT, const int* __restrict__ valid_lens)
{
    int b  = blockIdx.x >> 5;            // H_/HT == 32
    int h0 = (blockIdx.x & 31) * HT;
    int t  = threadIdx.x;                // k index
    int vlC = (valid_lens[b] + 63) & ~63;
    if (t >= vlC) return;                // wave-uniform exit
    const float4* krow4 = (const float4*)(keys + (size_t)(b * TK + t) * DIN);
    float acc[HT];
    #pragma unroll
    for (int hh = 0; hh < HT; ++hh) acc[hh] = 0.f;
    #pragma unroll 4
    for (int d4 = 0; d4 < DIN / 4; ++d4) {
        float4 kd = krow4[d4];
        const float* wrow = wk + 4 * d4 * H_ + h0;
        #pragma unroll
        for (int hh = 0; hh < HT; ++hh) acc[hh] = fmaf(kd.x, wrow[hh], acc[hh]);
        #pragma unroll
        for (int hh = 0; hh < HT; ++hh) acc[hh] = fmaf(kd.y, wrow[H_ + hh], acc[hh]);
        #pragma unroll
        for (int hh = 0; hh < HT; ++hh) acc[hh] = fmaf(kd.z, wrow[2 * H_ + hh], acc[hh]);
        #pragma unroll
        for (int hh = 0; hh < HT; ++hh) acc[hh] = fmaf(kd.w, wrow[3 * H_ + hh], acc[hh]);
    }
    #pragma unroll
    for (int hh = 0; hh < HT; ++hh)
        kpT[(b * H_ + h0 + hh) * TK + t] = acc[hh] * SCALE;
}

__device__ inline float waveMax(float v) {
    #pragma unroll
    for (int off = 32; off > 0; off >>= 1) v = fmaxf(v, __shfl_xor(v, off, 64));
    return v;
}
__device__ inline float waveSum(float v) {
    #pragma unroll
    for (int off = 32; off > 0; off >>= 1) v += __shfl_xor(v, off, 64);
    return v;
}

// ---------------- Kernel C: fused q-proj + scores(4 rows) + softmax + attn@V ----------------
// grid = B*(TQ/QT) = 512 blocks, 512 threads, __launch_bounds__(512,4): VGPR cap 128
// gives the scheduler room to keep the prefetched kv load in flight (R7's 32-VGPR
// squeeze serialized load->compute and capped VALUBusy at ~50%).
// Phase 1: wave w owns h in [32w,32w+32); lane l covers k=4l..4l+3 via one float4 load
// feeding 16 sigmoid terms; the NEXT iteration's load is issued before computing the
// current one (explicit prefetch, last iteration peeled).
__global__ __launch_bounds__(512, 4) void attn_kernel(
    const float* __restrict__ queries, const float* __restrict__ wq,
    const float* __restrict__ kpT,
    const float* __restrict__ values, const int* __restrict__ valid_lens,
    const float* __restrict__ wv, float* __restrict__ out)
{
    __shared__ float2 qs2[2][H_];          // [rowpair][h] scaled q-proj
    __shared__ float  wvL[H_];
    __shared__ float  scoreP[NW][QT][TK];  // 32 KB partial sums of wv*r; [0] reused ph3
    __shared__ float  attnT[TK][QT];       // k-major, float4-readable per k

    // XCD swizzle: 2 batches per XCD slot -> ~1 MB hot set per XCD L2.
    int bx  = blockIdx.x;
    int xcd = bx & 7;
    int i   = bx >> 3;                     // 0..63
    int b   = xcd + 8 * (i & 1);
    int q0  = (i >> 1) * QT;               // 0,4,...,124
    int t   = threadIdx.x;                 // 0..511
    int w   = t >> 6, l = t & 63;
    int vl  = valid_lens[b];

    // ---- phase 0: project 4 query rows; half-block rp handles row pair rp ----
    {
        int h = t & 255, rp = t >> 8;
        const float* qbase = queries + (size_t)(b * TQ + q0 + rp * 2) * DIN;  // uniform
        float a0 = 0.f, a1 = 0.f;
        #pragma unroll
        for (int d = 0; d < DIN; ++d) {
            float ww = wq[d * H_ + h];                // coalesced, L2-hot
            a0 = fmaf(qbase[d],       ww, a0);
            a1 = fmaf(qbase[DIN + d], ww, a1);
        }
        qs2[rp][h] = make_float2(a0 * SCALE, a1 * SCALE);
        if (t < 256) wvL[h] = wv[h];
    }
    __syncthreads();

    // ---- phase 1: wave w covers h in [32w,32w+32); lane l covers k=4l..4l+3 ----
    // accumulates sum(wv*r), r = sigmoid-like rcp(1+exp2(u)); tanh folded in phase 2.
    {
        const float4* kp4 = (const float4*)(kpT + (size_t)b * H_ * TK);
        float4 s0 = {0,0,0,0}, s1 = {0,0,0,0}, s2 = {0,0,0,0}, s3 = {0,0,0,0};
        int h0 = w * (H_ / NW);

        auto body = [&](int h, float4 kv) {
            float2 qA  = qs2[0][h];            // broadcast b64 (rows 0,1)
            float2 qB  = qs2[1][h];            // broadcast b64 (rows 2,3)
            float  wvh = wvL[h];
            float r;
            r = fast_rcp(fast_exp2(qA.x + kv.x) + 1.f); s0.x = fmaf(wvh, r, s0.x);
            r = fast_rcp(fast_exp2(qA.x + kv.y) + 1.f); s0.y = fmaf(wvh, r, s0.y);
            r = fast_rcp(fast_exp2(qA.x + kv.z) + 1.f); s0.z = fmaf(wvh, r, s0.z);
            r = fast_rcp(fast_exp2(qA.x + kv.w) + 1.f); s0.w = fmaf(wvh, r, s0.w);
            r = fast_rcp(fast_exp2(qA.y + kv.x) + 1.f); s1.x = fmaf(wvh, r, s1.x);
            r = fast_rcp(fast_exp2(qA.y + kv.y) + 1.f); s1.y = fmaf(wvh, r, s1.y);
            r = fast_rcp(fast_exp2(qA.y + kv.z) + 1.f); s1.z = fmaf(wvh, r, s1.z);
            r = fast_rcp(fast_exp2(qA.y + kv.w) + 1.f); s1.w = fmaf(wvh, r, s1.w);
            r = fast_rcp(fast_exp2(qB.x + kv.x) + 1.f); s2.x = fmaf(wvh, r, s2.x);
            r = fast_rcp(fast_exp2(qB.x + kv.y) + 1.f); s2.y = fmaf(wvh, r, s2.y);
            r = fast_rcp(fast_exp2(qB.x + kv.z) + 1.f); s2.z = fmaf(wvh, r, s2.z);
            r = fast_rcp(fast_exp2(qB.x + kv.w) + 1.f); s2.w = fmaf(wvh, r, s2.w);
            r = fast_rcp(fast_exp2(qB.y + kv.x) + 1.f); s3.x = fmaf(wvh, r, s3.x);
            r = fast_rcp(fast_exp2(qB.y + kv.y) + 1.f); s3.y = fmaf(wvh, r, s3.y);
            r = fast_rcp(fast_exp2(qB.y + kv.z) + 1.f); s3.z = fmaf(wvh, r, s3.z);
            r = fast_rcp(fast_exp2(qB.y + kv.w) + 1.f); s3.w = fmaf(wvh, r, s3.w);
        };

        float4 kv = kp4[(size_t)h0 * (TK / 4) + l];      // prime the pipe
        #pragma unroll 2
        for (int hh = 0; hh < H_ / NW - 1; ++hh) {
            float4 kvn = kp4[(size_t)(h0 + hh + 1) * (TK / 4) + l];  // prefetch next
            body(h0 + hh, kv);                                       // compute current
            kv = kvn;
        }
        body(h0 + H_ / NW - 1, kv);                      // peeled last iteration

        ((float4*)&scoreP[w][0][0])[l] = s0;             // b128 stores
        ((float4*)&scoreP[w][1][0])[l] = s1;
        ((float4*)&scoreP[w][2][0])[l] = s2;
        ((float4*)&scoreP[w][3][0])[l] = s3;
    }
    __syncthreads();

    // ---- phase 2: wave r (r<QT) softmaxes row q0+r; lane covers k=4l..4l+3 ----
    if (t < 64 * QT) {
        int r = w;
        // W = sum_h wv_h; score = W - 2*sum(wv*r)
        float W = waveSum(wvL[l] + wvL[l + 64] + wvL[l + 128] + wvL[l + 192]);
        float4 v = {0, 0, 0, 0};
        #pragma unroll
        for (int s = 0; s < NW; ++s) {
            float4 ps = ((const float4*)&scoreP[s][r][0])[l];
            v.x += ps.x; v.y += ps.y; v.z += ps.z; v.w += ps.w;
        }
        int k0 = 4 * l;
        v.x = (k0     < vl) ? fmaf(-2.f, v.x, W) : NEG;
        v.y = (k0 + 1 < vl) ? fmaf(-2.f, v.y, W) : NEG;
        v.z = (k0 + 2 < vl) ? fmaf(-2.f, v.z, W) : NEG;
        v.w = (k0 + 3 < vl) ? fmaf(-2.f, v.w, W) : NEG;
        float m  = waveMax(fmaxf(fmaxf(v.x, v.y), fmaxf(v.z, v.w)));
        // vl>0: masked p underflows to exactly 0 (matches ref). vl==0: uniform.
        float p0 = fast_exp2((v.x - m) * LOG2E);
        float p1 = fast_exp2((v.y - m) * LOG2E);
        float p2 = fast_exp2((v.z - m) * LOG2E);
        float p3 = fast_exp2((v.w - m) * LOG2E);
        float dr = fast_rcp(waveSum(p0 + p1 + p2 + p3));
        attnT[k0    ][r] = p0 * dr;
        attnT[k0 + 1][r] = p1 * dr;
        attnT[k0 + 2][r] = p2 * dr;
        attnT[k0 + 3][r] = p3 * dr;
    }
    __syncthreads();

    // ---- phase 3: half-block splits k-range, clipped to vl (weights for k>=vl are 0) ----
    {
        int half = t >> 8, v = t & 255;
        int kLim = (vl == 0) ? TK : vl;        // vl==0: uniform weights over all k
        int kBeg = half * (TK / 2);
        int kEnd = min(kBeg + TK / 2, kLim);   // half1 empty when kLim<=128
        const float*  vcol = values + (size_t)b * TK * DV + v;
        const float4* at4  = (const float4*)attnT;
        float o0 = 0.f, o1 = 0.f, o2 = 0.f, o3 = 0.f;
        #pragma unroll 4
        for (int k = kBeg; k < kEnd; ++k) {
            float  vv = vcol[k * DV];          // coalesced over v
            float4 a  = at4[k];                // broadcast b128
            o0 = fmaf(a.x, vv, o0);
            o1 = fmaf(a.y, vv, o1);
            o2 = fmaf(a.z, vv, o2);
            o3 = fmaf(a.w, vv, o3);
        }
        if (half == 1) {                       // stash partials (reuse scoreP[0])
            scoreP[0][0][v] = o0;
            scoreP[0][1][v] = o1;
            scoreP[0][2][v] = o2;
            scoreP[0][3][v] = o3;
        }
        __syncthreads();
        if (half == 0) {
            float* orow = out + (size_t)(b * TQ + q0) * DV + v;
            orow[0]      = o0 + scoreP[0][0][v];
            orow[DV]     = o1 + scoreP[0][1][v];
            orow[2 * DV] = o2 + scoreP[0][2][v];
            orow[3 * DV] = o3 + scoreP[0][3][v];
        }
    }
}

extern "C" void kernel_launch(void* const* d_in, const int* in_sizes, int n_in,
                              void* d_out, int out_size, void* d_ws, size_t ws_size,
                              hipStream_t stream) {
    const float* queries    = (const float*)d_in[0];
    const float* keys       = (const float*)d_in[1];
    const float* values     = (const float*)d_in[2];
    const int*   valid_lens = (const int*)  d_in[3];
    const float* wq         = (const float*)d_in[4];
    const float* wk         = (const float*)d_in[5];
    const float* wv         = (const float*)d_in[6];
    float* out = (float*)d_out;

    float* kpT = (float*)d_ws;   // [B,H,TK] = 4 MiB

    proj_k_kernel<<<B_ * (H_ / HT), 256, 0, stream>>>(keys, wk, kpT, valid_lens);
    attn_kernel<<<B_ * (TQ / QT), 512, 0, stream>>>(queries, wq, kpT, values,
                                                    valid_lens, wv, out);
}

// Round 9
// 101.203 us; speedup vs baseline: 1.1457x; 1.1092x over previous
//
#include <hip/hip_runtime.h>

#define B_  16
#define TQ  128
#define TK  256
#define DIN 64
#define H_  256
#define DV  256
#define HT  8          // h-cols per proj_k block
#define QT  4          // q-rows per attn block
#define NW  8          // waves per attn block (512 threads)
#define NEG -1000000.0f

// tanh(x) = 1 - 2*rcp(1 + e^{2x});  e^{2x} = exp2(SCALE*x), SCALE = 2*log2(e).
// Factorized: e^{2(q+k)} = Eq*Ek with Eq, Ek precomputed -> inner loop has NO exp.
#define SCALE  2.8853900817779268f
#define LOG2E  1.4426950408889634f

__device__ inline float fast_exp2(float x) { return __builtin_amdgcn_exp2f(x); }
__device__ inline float fast_rcp(float x)  { return __builtin_amdgcn_rcpf(x); }

// ---------------- Kernel B: EkT[b,h,k] = exp2(SCALE * sum_d keys[b,k,d]*wk[d,h]) --------
// grid = B*(H/HT) = 512 blocks, 256 threads (t = k). float4 keys loads.
// Skips k >= ceil64(vl): those entries stay poisoned (finite) and are masked downstream.
__global__ __launch_bounds__(256) void proj_k_kernel(
    const float* __restrict__ keys, const float* __restrict__ wk,
    float* __restrict__ EkT, const int* __restrict__ valid_lens)
{
    int b  = blockIdx.x >> 5;            // H_/HT == 32
    int h0 = (blockIdx.x & 31) * HT;
    int t  = threadIdx.x;                // k index
    int vlC = (valid_lens[b] + 63) & ~63;
    if (t >= vlC) return;                // wave-uniform exit
    const float4* krow4 = (const float4*)(keys + (size_t)(b * TK + t) * DIN);
    float acc[HT];
    #pragma unroll
    for (int hh = 0; hh < HT; ++hh) acc[hh] = 0.f;
    #pragma unroll 4
    for (int d4 = 0; d4 < DIN / 4; ++d4) {
        float4 kd = krow4[d4];
        const float* wrow = wk + 4 * d4 * H_ + h0;
        #pragma unroll
        for (int hh = 0; hh < HT; ++hh) acc[hh] = fmaf(kd.x, wrow[hh], acc[hh]);
        #pragma unroll
        for (int hh = 0; hh < HT; ++hh) acc[hh] = fmaf(kd.y, wrow[H_ + hh], acc[hh]);
        #pragma unroll
        for (int hh = 0; hh < HT; ++hh) acc[hh] = fmaf(kd.z, wrow[2 * H_ + hh], acc[hh]);
        #pragma unroll
        for (int hh = 0; hh < HT; ++hh) acc[hh] = fmaf(kd.w, wrow[3 * H_ + hh], acc[hh]);
    }
    #pragma unroll
    for (int hh = 0; hh < HT; ++hh)
        EkT[(b * H_ + h0 + hh) * TK + t] = fast_exp2(acc[hh] * SCALE);
}

__device__ inline float waveMax(float v) {
    #pragma unroll
    for (int off = 32; off > 0; off >>= 1) v = fmaxf(v, __shfl_xor(v, off, 64));
    return v;
}
__device__ inline float waveSum(float v) {
    #pragma unroll
    for (int off = 32; off > 0; off >>= 1) v += __shfl_xor(v, off, 64);
    return v;
}

// ---------------- Kernel C: fused q-proj + scores(4 rows) + softmax + attn@V ----------------
// grid = B*(TQ/QT) = 512 blocks, 512 threads.
// Phase 1 inner element: r = rcp(fma(Eq, Ek, 1)); s = fma(wv, r, s) -> 3 instrs, ONE
// transcendental (was 2 + adds). Saturation is exact: Eq*Ek -> inf gives r=0 (tanh=+1),
// -> 0 gives r=1 (tanh=-1). Score folded as W - 2*sum(wv*r) in phase 2.
__global__ __launch_bounds__(512, 4) void attn_kernel(
    const float* __restrict__ queries, const float* __restrict__ wq,
    const float* __restrict__ EkT,
    const float* __restrict__ values, const int* __restrict__ valid_lens,
    const float* __restrict__ wv, float* __restrict__ out)
{
    __shared__ float2 eq2[2][H_];          // [rowpair][h] Eq = exp2(SCALE*qproj)
    __shared__ float  wvL[H_];
    __shared__ float  scoreP[NW][QT][TK];  // 32 KB partial sums of wv*r; [0] reused ph3
    __shared__ float  attnT[TK][QT];       // k-major, float4-readable per k

    // XCD swizzle: 2 batches per XCD slot -> ~1 MB hot set per XCD L2.
    int bx  = blockIdx.x;
    int xcd = bx & 7;
    int i   = bx >> 3;                     // 0..63
    int b   = xcd + 8 * (i & 1);
    int q0  = (i >> 1) * QT;               // 0,4,...,124
    int t   = threadIdx.x;                 // 0..511
    int w   = t >> 6, l = t & 63;
    int vl  = valid_lens[b];

    // ---- phase 0: project 4 query rows; half-block rp handles row pair rp ----
    {
        int h = t & 255, rp = t >> 8;
        const float* qbase = queries + (size_t)(b * TQ + q0 + rp * 2) * DIN;  // uniform
        float a0 = 0.f, a1 = 0.f;
        #pragma unroll
        for (int d = 0; d < DIN; ++d) {
            float ww = wq[d * H_ + h];                // coalesced, L2-hot
            a0 = fmaf(qbase[d],       ww, a0);
            a1 = fmaf(qbase[DIN + d], ww, a1);
        }
        eq2[rp][h] = make_float2(fast_exp2(a0 * SCALE), fast_exp2(a1 * SCALE));
        if (t < 256) wvL[h] = wv[h];
    }
    __syncthreads();

    // ---- phase 1: wave w covers h in [32w,32w+32); lane l covers k=4l..4l+3 ----
    {
        const float4* ek4 = (const float4*)(EkT + (size_t)b * H_ * TK);
        float4 s0 = {0,0,0,0}, s1 = {0,0,0,0}, s2 = {0,0,0,0}, s3 = {0,0,0,0};
        int h0 = w * (H_ / NW);

        auto body = [&](int h, float4 kv) {
            float2 eA  = eq2[0][h];            // broadcast b64 (rows 0,1)
            float2 eB  = eq2[1][h];            // broadcast b64 (rows 2,3)
            float  wvh = wvL[h];
            float r;
            r = fast_rcp(fmaf(eA.x, kv.x, 1.f)); s0.x = fmaf(wvh, r, s0.x);
            r = fast_rcp(fmaf(eA.x, kv.y, 1.f)); s0.y = fmaf(wvh, r, s0.y);
            r = fast_rcp(fmaf(eA.x, kv.z, 1.f)); s0.z = fmaf(wvh, r, s0.z);
            r = fast_rcp(fmaf(eA.x, kv.w, 1.f)); s0.w = fmaf(wvh, r, s0.w);
            r = fast_rcp(fmaf(eA.y, kv.x, 1.f)); s1.x = fmaf(wvh, r, s1.x);
            r = fast_rcp(fmaf(eA.y, kv.y, 1.f)); s1.y = fmaf(wvh, r, s1.y);
            r = fast_rcp(fmaf(eA.y, kv.z, 1.f)); s1.z = fmaf(wvh, r, s1.z);
            r = fast_rcp(fmaf(eA.y, kv.w, 1.f)); s1.w = fmaf(wvh, r, s1.w);
            r = fast_rcp(fmaf(eB.x, kv.x, 1.f)); s2.x = fmaf(wvh, r, s2.x);
            r = fast_rcp(fmaf(eB.x, kv.y, 1.f)); s2.y = fmaf(wvh, r, s2.y);
            r = fast_rcp(fmaf(eB.x, kv.z, 1.f)); s2.z = fmaf(wvh, r, s2.z);
            r = fast_rcp(fmaf(eB.x, kv.w, 1.f)); s2.w = fmaf(wvh, r, s2.w);
            r = fast_rcp(fmaf(eB.y, kv.x, 1.f)); s3.x = fmaf(wvh, r, s3.x);
            r = fast_rcp(fmaf(eB.y, kv.y, 1.f)); s3.y = fmaf(wvh, r, s3.y);
            r = fast_rcp(fmaf(eB.y, kv.z, 1.f)); s3.z = fmaf(wvh, r, s3.z);
            r = fast_rcp(fmaf(eB.y, kv.w, 1.f)); s3.w = fmaf(wvh, r, s3.w);
        };

        float4 kv = ek4[(size_t)h0 * (TK / 4) + l];      // prime the pipe
        #pragma unroll 2
        for (int hh = 0; hh < H_ / NW - 1; ++hh) {
            float4 kvn = ek4[(size_t)(h0 + hh + 1) * (TK / 4) + l];  // prefetch next
            body(h0 + hh, kv);
            kv = kvn;
        }
        body(h0 + H_ / NW - 1, kv);                      // peeled last iteration

        ((float4*)&scoreP[w][0][0])[l] = s0;             // b128 stores
        ((float4*)&scoreP[w][1][0])[l] = s1;
        ((float4*)&scoreP[w][2][0])[l] = s2;
        ((float4*)&scoreP[w][3][0])[l] = s3;
    }
    __syncthreads();

    // ---- phase 2: wave r (r<QT) softmaxes row q0+r; lane covers k=4l..4l+3 ----
    if (t < 64 * QT) {
        int r = w;
        // W = sum_h wv_h; score = W - 2*sum(wv*r)
        float W = waveSum(wvL[l] + wvL[l + 64] + wvL[l + 128] + wvL[l + 192]);
        float4 v = {0, 0, 0, 0};
        #pragma unroll
        for (int s = 0; s < NW; ++s) {
            float4 ps = ((const float4*)&scoreP[s][r][0])[l];
            v.x += ps.x; v.y += ps.y; v.z += ps.z; v.w += ps.w;
        }
        int k0 = 4 * l;
        v.x = (k0     < vl) ? fmaf(-2.f, v.x, W) : NEG;
        v.y = (k0 + 1 < vl) ? fmaf(-2.f, v.y, W) : NEG;
        v.z = (k0 + 2 < vl) ? fmaf(-2.f, v.z, W) : NEG;
        v.w = (k0 + 3 < vl) ? fmaf(-2.f, v.w, W) : NEG;
        float m  = waveMax(fmaxf(fmaxf(v.x, v.y), fmaxf(v.z, v.w)));
        // vl>0: masked p underflows to exactly 0 (matches ref). vl==0: uniform.
        float p0 = fast_exp2((v.x - m) * LOG2E);
        float p1 = fast_exp2((v.y - m) * LOG2E);
        float p2 = fast_exp2((v.z - m) * LOG2E);
        float p3 = fast_exp2((v.w - m) * LOG2E);
        float dr = fast_rcp(waveSum(p0 + p1 + p2 + p3));
        attnT[k0    ][r] = p0 * dr;
        attnT[k0 + 1][r] = p1 * dr;
        attnT[k0 + 2][r] = p2 * dr;
        attnT[k0 + 3][r] = p3 * dr;
    }
    __syncthreads();

    // ---- phase 3: half-block splits k-range, clipped to vl (weights for k>=vl are 0) ----
    {
        int half = t >> 8, v = t & 255;
        int kLim = (vl == 0) ? TK : vl;        // vl==0: uniform weights over all k
        int kBeg = half * (TK / 2);
        int kEnd = min(kBeg + TK / 2, kLim);   // half1 empty when kLim<=128
        const float*  vcol = values + (size_t)b * TK * DV + v;
        const float4* at4  = (const float4*)attnT;
        float o0 = 0.f, o1 = 0.f, o2 = 0.f, o3 = 0.f;
        #pragma unroll 4
        for (int k = kBeg; k < kEnd; ++k) {
            float  vv = vcol[k * DV];          // coalesced over v
            float4 a  = at4[k];                // broadcast b128
            o0 = fmaf(a.x, vv, o0);
            o1 = fmaf(a.y, vv, o1);
            o2 = fmaf(a.z, vv, o2);
            o3 = fmaf(a.w, vv, o3);
        }
        if (half == 1) {                       // stash partials (reuse scoreP[0])
            scoreP[0][0][v] = o0;
            scoreP[0][1][v] = o1;
            scoreP[0][2][v] = o2;
            scoreP[0][3][v] = o3;
        }
        __syncthreads();
        if (half == 0) {
            float* orow = out + (size_t)(b * TQ + q0) * DV + v;
            orow[0]      = o0 + scoreP[0][0][v];
            orow[DV]     = o1 + scoreP[0][1][v];
            orow[2 * DV] = o2 + scoreP[0][2][v];
            orow[3 * DV] = o3 + scoreP[0][3][v];
        }
    }
}

extern "C" void kernel_launch(void* const* d_in, const int* in_sizes, int n_in,
                              void* d_out, int out_size, void* d_ws, size_t ws_size,
                              hipStream_t stream) {
    const float* queries    = (const float*)d_in[0];
    const float* keys       = (const float*)d_in[1];
    const float* values     = (const float*)d_in[2];
    const int*   valid_lens = (const int*)  d_in[3];
    const float* wq         = (const float*)d_in[4];
    const float* wk         = (const float*)d_in[5];
    const float* wv         = (const float*)d_in[6];
    float* out = (float*)d_out;

    float* EkT = (float*)d_ws;   // [B,H,TK] = 4 MiB, holds exp2(SCALE*kproj)

    proj_k_kernel<<<B_ * (H_ / HT), 256, 0, stream>>>(keys, wk, EkT, valid_lens);
    attn_kernel<<<B_ * (TQ / QT), 512, 0, stream>>>(queries, wq, EkT, values,
                                                    valid_lens, wv, out);
}

// Round 10
// 100.377 us; speedup vs baseline: 1.1551x; 1.0082x over previous
//
#include <hip/hip_runtime.h>

#define B_  16
#define TQ  128
#define TK  256
#define DIN 64
#define H_  256
#define DV  256
#define HT  8          // h-cols per proj_k block
#define QT  4          // q-rows per attn block
#define NW  8          // waves per attn block (512 threads)
#define NEG -1000000.0f

// tanh(x) = 1 - 2*rcp(1 + e^{2x});  e^{2x} = exp2(SCALE*x), SCALE = 2*log2(e).
// Factorized: e^{2(q+k)} = Eq*Ek precomputed -> inner loop has NO exp.
// Reciprocals batched 2-way: 1/a = b*rcp(ab), 1/b = a*rcp(ab) -> half the v_rcp.
#define SCALE  2.8853900817779268f
#define LOG2E  1.4426950408889634f

__device__ inline float fast_exp2(float x) { return __builtin_amdgcn_exp2f(x); }
__device__ inline float fast_rcp(float x)  { return __builtin_amdgcn_rcpf(x); }

// float2 helpers written to SLP-vectorize into v_pk_fma_f32 / v_pk_mul_f32
__device__ inline float2 f2fma(float2 a, float2 b, float2 c) {
    return make_float2(fmaf(a.x, b.x, c.x), fmaf(a.y, b.y, c.y));
}
__device__ inline float2 f2mul(float2 a, float2 b) {
    return make_float2(a.x * b.x, a.y * b.y);
}

// ---------------- Kernel B: EkT[b,h,k] = exp2(SCALE * sum_d keys[b,k,d]*wk[d,h]) --------
// grid = B*(H/HT) = 512 blocks, 256 threads (t = k). float4 keys loads.
// Skips k >= ceil64(vl): those entries stay poisoned (finite) and are masked downstream.
__global__ __launch_bounds__(256) void proj_k_kernel(
    const float* __restrict__ keys, const float* __restrict__ wk,
    float* __restrict__ EkT, const int* __restrict__ valid_lens)
{
    int b  = blockIdx.x >> 5;            // H_/HT == 32
    int h0 = (blockIdx.x & 31) * HT;
    int t  = threadIdx.x;                // k index
    int vlC = (valid_lens[b] + 63) & ~63;
    if (t >= vlC) return;                // wave-uniform exit
    const float4* krow4 = (const float4*)(keys + (size_t)(b * TK + t) * DIN);
    float acc[HT];
    #pragma unroll
    for (int hh = 0; hh < HT; ++hh) acc[hh] = 0.f;
    #pragma unroll 4
    for (int d4 = 0; d4 < DIN / 4; ++d4) {
        float4 kd = krow4[d4];
        const float* wrow = wk + 4 * d4 * H_ + h0;
        #pragma unroll
        for (int hh = 0; hh < HT; ++hh) acc[hh] = fmaf(kd.x, wrow[hh], acc[hh]);
        #pragma unroll
        for (int hh = 0; hh < HT; ++hh) acc[hh] = fmaf(kd.y, wrow[H_ + hh], acc[hh]);
        #pragma unroll
        for (int hh = 0; hh < HT; ++hh) acc[hh] = fmaf(kd.z, wrow[2 * H_ + hh], acc[hh]);
        #pragma unroll
        for (int hh = 0; hh < HT; ++hh) acc[hh] = fmaf(kd.w, wrow[3 * H_ + hh], acc[hh]);
    }
    #pragma unroll
    for (int hh = 0; hh < HT; ++hh)
        EkT[(b * H_ + h0 + hh) * TK + t] = fast_exp2(acc[hh] * SCALE);
}

__device__ inline float waveMax(float v) {
    #pragma unroll
    for (int off = 32; off > 0; off >>= 1) v = fmaxf(v, __shfl_xor(v, off, 64));
    return v;
}
__device__ inline float waveSum(float v) {
    #pragma unroll
    for (int off = 32; off > 0; off >>= 1) v += __shfl_xor(v, off, 64);
    return v;
}

// ---------------- Kernel C: fused q-proj + scores(4 rows) + softmax + attn@V ----------------
// grid = B*(TQ/QT) = 512 blocks, 512 threads.
// Phase 1 per row per 4 k's: 2 pk_fma (d=1+Eq*Ek) + 2 mul (pair prod) + 2 rcp +
// 2 pk_mul (recover) + 2 pk_fma (acc) -> ~32 exec-cyc; rcp count HALVED vs R9.
__global__ __launch_bounds__(512, 4) void attn_kernel(
    const float* __restrict__ queries, const float* __restrict__ wq,
    const float* __restrict__ EkT,
    const float* __restrict__ values, const int* __restrict__ valid_lens,
    const float* __restrict__ wv, float* __restrict__ out)
{
    __shared__ float2 eq2[2][H_];          // [rowpair][h] Eq = exp2(SCALE*qproj)
    __shared__ float  wvL[H_];
    __shared__ float  scoreP[NW][QT][TK];  // 32 KB partial sums of wv*r; [0] reused ph3
    __shared__ float  attnT[TK][QT];       // k-major, float4-readable per k

    // XCD swizzle: 2 batches per XCD slot -> ~1 MB hot set per XCD L2.
    int bx  = blockIdx.x;
    int xcd = bx & 7;
    int i   = bx >> 3;                     // 0..63
    int b   = xcd + 8 * (i & 1);
    int q0  = (i >> 1) * QT;               // 0,4,...,124
    int t   = threadIdx.x;                 // 0..511
    int w   = t >> 6, l = t & 63;
    int vl  = valid_lens[b];

    // ---- phase 0: project 4 query rows; half-block rp handles row pair rp ----
    {
        int h = t & 255, rp = t >> 8;
        const float* qbase = queries + (size_t)(b * TQ + q0 + rp * 2) * DIN;  // uniform
        float a0 = 0.f, a1 = 0.f;
        #pragma unroll
        for (int d = 0; d < DIN; ++d) {
            float ww = wq[d * H_ + h];                // coalesced, L2-hot
            a0 = fmaf(qbase[d],       ww, a0);
            a1 = fmaf(qbase[DIN + d], ww, a1);
        }
        eq2[rp][h] = make_float2(fast_exp2(a0 * SCALE), fast_exp2(a1 * SCALE));
        if (t < 256) wvL[h] = wv[h];
    }
    __syncthreads();

    // ---- phase 1: wave w covers h in [32w,32w+32); lane l covers k=4l..4l+3 ----
    {
        const float4* ek4 = (const float4*)(EkT + (size_t)b * H_ * TK);
        // per row: two float2 accumulators (k pair xy, k pair zw)
        float2 sA0={0,0}, sA1={0,0}, sB0={0,0}, sB1={0,0};
        float2 sC0={0,0}, sC1={0,0}, sD0={0,0}, sD1={0,0};
        int h0 = w * (H_ / NW);
        const float2 ones = make_float2(1.f, 1.f);

        auto row = [&](float eq, float2 kxy, float2 kzw, float2 w2,
                       float2& sp0, float2& sp1) {
            float2 e2 = make_float2(eq, eq);
            float2 d0 = f2fma(e2, kxy, ones);          // pk_fma
            float2 d1 = f2fma(e2, kzw, ones);          // pk_fma
            float rp0 = fast_rcp(d0.x * d0.y);         // 1 rcp per 2 elems
            float rp1 = fast_rcp(d1.x * d1.y);
            float2 r0 = f2mul(make_float2(d0.y, d0.x), make_float2(rp0, rp0)); // pk_mul
            float2 r1 = f2mul(make_float2(d1.y, d1.x), make_float2(rp1, rp1));
            sp0 = f2fma(w2, r0, sp0);                  // pk_fma
            sp1 = f2fma(w2, r1, sp1);
        };

        auto body = [&](int h, float4 kv) {
            float2 eA  = eq2[0][h];                    // broadcast b64 (rows 0,1)
            float2 eB  = eq2[1][h];                    // broadcast b64 (rows 2,3)
            float  wvh = wvL[h];
            float2 w2  = make_float2(wvh, wvh);
            float2 kxy = make_float2(kv.x, kv.y);
            float2 kzw = make_float2(kv.z, kv.w);
            row(eA.x, kxy, kzw, w2, sA0, sA1);
            row(eA.y, kxy, kzw, w2, sB0, sB1);
            row(eB.x, kxy, kzw, w2, sC0, sC1);
            row(eB.y, kxy, kzw, w2, sD0, sD1);
        };

        float4 kv = ek4[(size_t)h0 * (TK / 4) + l];    // prime the pipe
        #pragma unroll 2
        for (int hh = 0; hh < H_ / NW - 1; ++hh) {
            float4 kvn = ek4[(size_t)(h0 + hh + 1) * (TK / 4) + l];  // prefetch next
            body(h0 + hh, kv);
            kv = kvn;
        }
        body(h0 + H_ / NW - 1, kv);                    // peeled last iteration

        ((float4*)&scoreP[w][0][0])[l] = make_float4(sA0.x, sA0.y, sA1.x, sA1.y);
        ((float4*)&scoreP[w][1][0])[l] = make_float4(sB0.x, sB0.y, sB1.x, sB1.y);
        ((float4*)&scoreP[w][2][0])[l] = make_float4(sC0.x, sC0.y, sC1.x, sC1.y);
        ((float4*)&scoreP[w][3][0])[l] = make_float4(sD0.x, sD0.y, sD1.x, sD1.y);
    }
    __syncthreads();

    // ---- phase 2: wave r (r<QT) softmaxes row q0+r; lane covers k=4l..4l+3 ----
    if (t < 64 * QT) {
        int r = w;
        // W = sum_h wv_h; score = W - 2*sum(wv*r)
        float W = waveSum(wvL[l] + wvL[l + 64] + wvL[l + 128] + wvL[l + 192]);
        float4 v = {0, 0, 0, 0};
        #pragma unroll
        for (int s = 0; s < NW; ++s) {
            float4 ps = ((const float4*)&scoreP[s][r][0])[l];
            v.x += ps.x; v.y += ps.y; v.z += ps.z; v.w += ps.w;
        }
        int k0 = 4 * l;
        v.x = (k0     < vl) ? fmaf(-2.f, v.x, W) : NEG;
        v.y = (k0 + 1 < vl) ? fmaf(-2.f, v.y, W) : NEG;
        v.z = (k0 + 2 < vl) ? fmaf(-2.f, v.z, W) : NEG;
        v.w = (k0 + 3 < vl) ? fmaf(-2.f, v.w, W) : NEG;
        float m  = waveMax(fmaxf(fmaxf(v.x, v.y), fmaxf(v.z, v.w)));
        // vl>0: masked p underflows to exactly 0 (matches ref). vl==0: uniform.
        float p0 = fast_exp2((v.x - m) * LOG2E);
        float p1 = fast_exp2((v.y - m) * LOG2E);
        float p2 = fast_exp2((v.z - m) * LOG2E);
        float p3 = fast_exp2((v.w - m) * LOG2E);
        float dr = fast_rcp(waveSum(p0 + p1 + p2 + p3));
        attnT[k0    ][r] = p0 * dr;
        attnT[k0 + 1][r] = p1 * dr;
        attnT[k0 + 2][r] = p2 * dr;
        attnT[k0 + 3][r] = p3 * dr;
    }
    __syncthreads();

    // ---- phase 3: half-block splits k-range, clipped to vl (weights for k>=vl are 0) ----
    {
        int half = t >> 8, v = t & 255;
        int kLim = (vl == 0) ? TK : vl;        // vl==0: uniform weights over all k
        int kBeg = half * (TK / 2);
        int kEnd = min(kBeg + TK / 2, kLim);   // half1 empty when kLim<=128
        const float*  vcol = values + (size_t)b * TK * DV + v;
        const float4* at4  = (const float4*)attnT;
        float2 oA = {0, 0}, oB = {0, 0};
        #pragma unroll 4
        for (int k = kBeg; k < kEnd; ++k) {
            float  vv = vcol[k * DV];          // coalesced over v
            float4 a  = at4[k];                // broadcast b128
            float2 v2 = make_float2(vv, vv);
            oA = f2fma(make_float2(a.x, a.y), v2, oA);   // pk_fma
            oB = f2fma(make_float2(a.z, a.w), v2, oB);   // pk_fma
        }
        if (half == 1) {                       // stash partials (reuse scoreP[0])
            scoreP[0][0][v] = oA.x;
            scoreP[0][1][v] = oA.y;
            scoreP[0][2][v] = oB.x;
            scoreP[0][3][v] = oB.y;
        }
        __syncthreads();
        if (half == 0) {
            float* orow = out + (size_t)(b * TQ + q0) * DV + v;
            orow[0]      = oA.x + scoreP[0][0][v];
            orow[DV]     = oA.y + scoreP[0][1][v];
            orow[2 * DV] = oB.x + scoreP[0][2][v];
            orow[3 * DV] = oB.y + scoreP[0][3][v];
        }
    }
}

extern "C" void kernel_launch(void* const* d_in, const int* in_sizes, int n_in,
                              void* d_out, int out_size, void* d_ws, size_t ws_size,
                              hipStream_t stream) {
    const float* queries    = (const float*)d_in[0];
    const float* keys       = (const float*)d_in[1];
    const float* values     = (const float*)d_in[2];
    const int*   valid_lens = (const int*)  d_in[3];
    const float* wq         = (const float*)d_in[4];
    const float* wk         = (const float*)d_in[5];
    const float* wv         = (const float*)d_in[6];
    float* out = (float*)d_out;

    float* EkT = (float*)d_ws;   // [B,H,TK] = 4 MiB, holds exp2(SCALE*kproj)

    proj_k_kernel<<<B_ * (H_ / HT), 256, 0, stream>>>(keys, wk, EkT, valid_lens);
    attn_kernel<<<B_ * (TQ / QT), 512, 0, stream>>>(queries, wq, EkT, values,
                                                    valid_lens, wv, out);
}

// Round 11
// 100.075 us; speedup vs baseline: 1.1586x; 1.0030x over previous
//
#include <hip/hip_runtime.h>

#define B_  16
#define TQ  128
#define TK  256
#define DIN 64
#define H_  256
#define DV  256
#define HT  8          // h-cols per proj_k block
#define QT  4          // q-rows per attn block
#define NW  8          // waves per attn block (512 threads)
#define NEG -1000000.0f

// tanh(x) = 1 - 2*rcp(1 + e^{2x});  e^{2x} = exp2(SCALE*x), SCALE = 2*log2(e).
// Factorized: e^{2(q+k)} = Eq*Ek precomputed -> inner loop has NO exp.
// Reciprocals batched 2-way: 1/a = b*rcp(ab), 1/b = a*rcp(ab) -> half the v_rcp.
#define SCALE  2.8853900817779268f
#define LOG2E  1.4426950408889634f

typedef float v2f __attribute__((ext_vector_type(2)));

__device__ inline float fast_exp2(float x) { return __builtin_amdgcn_exp2f(x); }
__device__ inline float fast_rcp(float x)  { return __builtin_amdgcn_rcpf(x); }
// lowers to llvm.fma.v2f32 -> v_pk_fma_f32 on gfx950 (real packed math)
__device__ inline v2f v2fma(v2f a, v2f b, v2f c) {
    return __builtin_elementwise_fma(a, b, c);
}

// ---------------- Kernel B: EkT[b,h,k] = exp2(SCALE * sum_d keys[b,k,d]*wk[d,h]) --------
// grid = B*(H/HT) = 512 blocks, 256 threads (t = k). float4 keys loads.
// Skips k >= ceil64(vl): those entries stay poisoned (finite) and are masked downstream.
__global__ __launch_bounds__(256) void proj_k_kernel(
    const float* __restrict__ keys, const float* __restrict__ wk,
    float* __restrict__ EkT, const int* __restrict__ valid_lens)
{
    int b  = blockIdx.x >> 5;            // H_/HT == 32
    int h0 = (blockIdx.x & 31) * HT;
    int t  = threadIdx.x;                // k index
    int vlC = (valid_lens[b] + 63) & ~63;
    if (t >= vlC) return;                // wave-uniform exit
    const float4* krow4 = (const float4*)(keys + (size_t)(b * TK + t) * DIN);
    float acc[HT];
    #pragma unroll
    for (int hh = 0; hh < HT; ++hh) acc[hh] = 0.f;
    #pragma unroll 4
    for (int d4 = 0; d4 < DIN / 4; ++d4) {
        float4 kd = krow4[d4];
        const float* wrow = wk + 4 * d4 * H_ + h0;
        #pragma unroll
        for (int hh = 0; hh < HT; ++hh) acc[hh] = fmaf(kd.x, wrow[hh], acc[hh]);
        #pragma unroll
        for (int hh = 0; hh < HT; ++hh) acc[hh] = fmaf(kd.y, wrow[H_ + hh], acc[hh]);
        #pragma unroll
        for (int hh = 0; hh < HT; ++hh) acc[hh] = fmaf(kd.z, wrow[2 * H_ + hh], acc[hh]);
        #pragma unroll
        for (int hh = 0; hh < HT; ++hh) acc[hh] = fmaf(kd.w, wrow[3 * H_ + hh], acc[hh]);
    }
    #pragma unroll
    for (int hh = 0; hh < HT; ++hh)
        EkT[(b * H_ + h0 + hh) * TK + t] = fast_exp2(acc[hh] * SCALE);
}

__device__ inline float waveMax(float v) {
    #pragma unroll
    for (int off = 32; off > 0; off >>= 1) v = fmaxf(v, __shfl_xor(v, off, 64));
    return v;
}
__device__ inline float waveSum(float v) {
    #pragma unroll
    for (int off = 32; off > 0; off >>= 1) v += __shfl_xor(v, off, 64);
    return v;
}

// ---------------- Kernel C: fused q-proj + scores(4 rows) + softmax + attn@V ----------------
// grid = B*(TQ/QT) = 512 blocks, 512 threads.
// Phase 1 per row per 4 k's (as v_pk ops): 2 pk_fma (d=1+Eq*Ek) + 2 mul (pair prod) +
// 2 rcp + 2 pk_mul (recover) + 2 pk_fma (acc) -> VALU ~16 cyc/row, trans 16 cyc/row.
__global__ __launch_bounds__(512, 4) void attn_kernel(
    const float* __restrict__ queries, const float* __restrict__ wq,
    const float* __restrict__ EkT,
    const float* __restrict__ values, const int* __restrict__ valid_lens,
    const float* __restrict__ wv, float* __restrict__ out)
{
    __shared__ float2 eq2[2][H_];          // [rowpair][h] Eq = exp2(SCALE*qproj)
    __shared__ float  wvL[H_];
    __shared__ float  scoreP[NW][QT][TK];  // 32 KB partial sums of wv*r; [0] reused ph3
    __shared__ float  attnT[TK][QT];       // k-major, float4-readable per k

    // XCD swizzle: 2 batches per XCD slot -> ~1 MB hot set per XCD L2.
    int bx  = blockIdx.x;
    int xcd = bx & 7;
    int i   = bx >> 3;                     // 0..63
    int b   = xcd + 8 * (i & 1);
    int q0  = (i >> 1) * QT;               // 0,4,...,124
    int t   = threadIdx.x;                 // 0..511
    int w   = t >> 6, l = t & 63;
    int vl  = valid_lens[b];

    // ---- phase 0: project 4 query rows; half-block rp handles row pair rp ----
    {
        int h = t & 255, rp = t >> 8;
        const float* qbase = queries + (size_t)(b * TQ + q0 + rp * 2) * DIN;  // uniform
        float a0 = 0.f, a1 = 0.f;
        #pragma unroll
        for (int d = 0; d < DIN; ++d) {
            float ww = wq[d * H_ + h];                // coalesced, L2-hot
            a0 = fmaf(qbase[d],       ww, a0);
            a1 = fmaf(qbase[DIN + d], ww, a1);
        }
        eq2[rp][h] = make_float2(fast_exp2(a0 * SCALE), fast_exp2(a1 * SCALE));
        if (t < 256) wvL[h] = wv[h];
    }
    __syncthreads();

    // ---- phase 1: wave w covers h in [32w,32w+32); lane l covers k=4l..4l+3 ----
    {
        const float4* ek4 = (const float4*)(EkT + (size_t)b * H_ * TK);
        // per row: two v2f accumulators (k pair xy, k pair zw)
        v2f sA0={0,0}, sA1={0,0}, sB0={0,0}, sB1={0,0};
        v2f sC0={0,0}, sC1={0,0}, sD0={0,0}, sD1={0,0};
        int h0 = w * (H_ / NW);
        const v2f one2 = {1.f, 1.f};

        auto row = [&](float eq, v2f kxy, v2f kzw, v2f w2, v2f& sp0, v2f& sp1) {
            v2f e2 = {eq, eq};
            v2f d0 = v2fma(e2, kxy, one2);             // v_pk_fma_f32
            v2f d1 = v2fma(e2, kzw, one2);
            float rp0 = fast_rcp(d0.x * d0.y);         // 1 v_rcp per 2 elems
            float rp1 = fast_rcp(d1.x * d1.y);
            v2f r0 = (v2f){d0.y, d0.x} * (v2f){rp0, rp0};   // v_pk_mul_f32 (op_sel swap)
            v2f r1 = (v2f){d1.y, d1.x} * (v2f){rp1, rp1};
            sp0 = v2fma(w2, r0, sp0);                  // v_pk_fma_f32
            sp1 = v2fma(w2, r1, sp1);
        };

        auto body = [&](int h, float4 kv) {
            float2 eA  = eq2[0][h];                    // broadcast b64 (rows 0,1)
            float2 eB  = eq2[1][h];                    // broadcast b64 (rows 2,3)
            float  wvh = wvL[h];
            v2f w2  = {wvh, wvh};
            v2f kxy = {kv.x, kv.y};
            v2f kzw = {kv.z, kv.w};
            row(eA.x, kxy, kzw, w2, sA0, sA1);
            row(eA.y, kxy, kzw, w2, sB0, sB1);
            row(eB.x, kxy, kzw, w2, sC0, sC1);
            row(eB.y, kxy, kzw, w2, sD0, sD1);
        };

        float4 kv = ek4[(size_t)h0 * (TK / 4) + l];    // prime the pipe
        #pragma unroll 2
        for (int hh = 0; hh < H_ / NW - 1; ++hh) {
            float4 kvn = ek4[(size_t)(h0 + hh + 1) * (TK / 4) + l];  // prefetch next
            body(h0 + hh, kv);
            kv = kvn;
        }
        body(h0 + H_ / NW - 1, kv);                    // peeled last iteration

        ((float4*)&scoreP[w][0][0])[l] = make_float4(sA0.x, sA0.y, sA1.x, sA1.y);
        ((float4*)&scoreP[w][1][0])[l] = make_float4(sB0.x, sB0.y, sB1.x, sB1.y);
        ((float4*)&scoreP[w][2][0])[l] = make_float4(sC0.x, sC0.y, sC1.x, sC1.y);
        ((float4*)&scoreP[w][3][0])[l] = make_float4(sD0.x, sD0.y, sD1.x, sD1.y);
    }
    __syncthreads();

    // ---- phase 2: wave r (r<QT) softmaxes row q0+r; lane covers k=4l..4l+3 ----
    if (t < 64 * QT) {
        int r = w;
        // W = sum_h wv_h; score = W - 2*sum(wv*r)
        float W = waveSum(wvL[l] + wvL[l + 64] + wvL[l + 128] + wvL[l + 192]);
        float4 v = {0, 0, 0, 0};
        #pragma unroll
        for (int s = 0; s < NW; ++s) {
            float4 ps = ((const float4*)&scoreP[s][r][0])[l];
            v.x += ps.x; v.y += ps.y; v.z += ps.z; v.w += ps.w;
        }
        int k0 = 4 * l;
        v.x = (k0     < vl) ? fmaf(-2.f, v.x, W) : NEG;
        v.y = (k0 + 1 < vl) ? fmaf(-2.f, v.y, W) : NEG;
        v.z = (k0 + 2 < vl) ? fmaf(-2.f, v.z, W) : NEG;
        v.w = (k0 + 3 < vl) ? fmaf(-2.f, v.w, W) : NEG;
        float m  = waveMax(fmaxf(fmaxf(v.x, v.y), fmaxf(v.z, v.w)));
        // vl>0: masked p underflows to exactly 0 (matches ref). vl==0: uniform.
        float p0 = fast_exp2((v.x - m) * LOG2E);
        float p1 = fast_exp2((v.y - m) * LOG2E);
        float p2 = fast_exp2((v.z - m) * LOG2E);
        float p3 = fast_exp2((v.w - m) * LOG2E);
        float dr = fast_rcp(waveSum(p0 + p1 + p2 + p3));
        attnT[k0    ][r] = p0 * dr;
        attnT[k0 + 1][r] = p1 * dr;
        attnT[k0 + 2][r] = p2 * dr;
        attnT[k0 + 3][r] = p3 * dr;
    }
    __syncthreads();

    // ---- phase 3: half-block splits k-range, clipped to vl (weights for k>=vl are 0) ----
    {
        int half = t >> 8, v = t & 255;
        int kLim = (vl == 0) ? TK : vl;        // vl==0: uniform weights over all k
        int kBeg = half * (TK / 2);
        int kEnd = min(kBeg + TK / 2, kLim);   // half1 empty when kLim<=128
        const float*  vcol = values + (size_t)b * TK * DV + v;
        const float4* at4  = (const float4*)attnT;
        v2f oA = {0, 0}, oB = {0, 0};
        #pragma unroll 4
        for (int k = kBeg; k < kEnd; ++k) {
            float  vv = vcol[k * DV];          // coalesced over v
            float4 a  = at4[k];                // broadcast b128
            v2f v2 = {vv, vv};
            oA = v2fma((v2f){a.x, a.y}, v2, oA);   // v_pk_fma_f32
            oB = v2fma((v2f){a.z, a.w}, v2, oB);
        }
        if (half == 1) {                       // stash partials (reuse scoreP[0])
            scoreP[0][0][v] = oA.x;
            scoreP[0][1][v] = oA.y;
            scoreP[0][2][v] = oB.x;
            scoreP[0][3][v] = oB.y;
        }
        __syncthreads();
        if (half == 0) {
            float* orow = out + (size_t)(b * TQ + q0) * DV + v;
            orow[0]      = oA.x + scoreP[0][0][v];
            orow[DV]     = oA.y + scoreP[0][1][v];
            orow[2 * DV] = oB.x + scoreP[0][2][v];
            orow[3 * DV] = oB.y + scoreP[0][3][v];
        }
    }
}

extern "C" void kernel_launch(void* const* d_in, const int* in_sizes, int n_in,
                              void* d_out, int out_size, void* d_ws, size_t ws_size,
                              hipStream_t stream) {
    const float* queries    = (const float*)d_in[0];
    const float* keys       = (const float*)d_in[1];
    const float* values     = (const float*)d_in[2];
    const int*   valid_lens = (const int*)  d_in[3];
    const float* wq         = (const float*)d_in[4];
    const float* wk         = (const float*)d_in[5];
    const float* wv         = (const float*)d_in[6];
    float* out = (float*)d_out;

    float* EkT = (float*)d_ws;   // [B,H,TK] = 4 MiB, holds exp2(SCALE*kproj)

    proj_k_kernel<<<B_ * (H_ / HT), 256, 0, stream>>>(keys, wk, EkT, valid_lens);
    attn_kernel<<<B_ * (TQ / QT), 512, 0, stream>>>(queries, wq, EkT, values,
                                                    valid_lens, wv, out);
}

// Round 12
// 97.922 us; speedup vs baseline: 1.1841x; 1.0220x over previous
//
#include <hip/hip_runtime.h>

#define B_  16
#define TQ  128
#define TK  256
#define DIN 64
#define H_  256
#define DV  256
#define HT  8          // h-cols per proj_k block
#define QT  4          // q-rows per attn block
#define NW  8          // waves per attn block (512 threads)
#define NEG -1000000.0f

// tanh(x) = 1 - 2*rcp(1 + e^{2x});  e^{2x} = exp2(SCALE*x), SCALE = 2*log2(e).
// Factorized: e^{2(q+k)} = Eq*Ek, both precomputed -> hot loop has NO exp, NO LDS.
#define SCALE  2.8853900817779268f
#define LOG2E  1.4426950408889634f

__device__ inline float fast_exp2(float x) { return __builtin_amdgcn_exp2f(x); }
__device__ inline float fast_rcp(float x)  { return __builtin_amdgcn_rcpf(x); }

// ---------------- Kernel B (fused producers) ----------------
// blocks 0..511:    EkT[b,h,k] = exp2(SCALE * sum_d keys[b,k,d]*wk[d,h])   (t = k)
// blocks 512..1023: EqW[b,g,h] = float4 of exp2(SCALE * qproj) for rows 4g..4g+3 (t = h)
__global__ __launch_bounds__(256) void proj_kernel(
    const float* __restrict__ keys, const float* __restrict__ wk,
    const float* __restrict__ queries, const float* __restrict__ wq,
    float* __restrict__ EkT, float4* __restrict__ EqW,
    const int* __restrict__ valid_lens)
{
    int bx = blockIdx.x;
    int t  = threadIdx.x;
    if (bx < 512) {
        // ---- K-projection -> exp, transposed [b][h][k] ----
        int b  = bx >> 5;                // H_/HT == 32
        int h0 = (bx & 31) * HT;
        int vlC = (valid_lens[b] + 63) & ~63;
        if (t >= vlC) return;            // wave-uniform exit; skipped entries stay
                                         // poisoned (finite) and are masked later
        const float4* krow4 = (const float4*)(keys + (size_t)(b * TK + t) * DIN);
        float acc[HT];
        #pragma unroll
        for (int hh = 0; hh < HT; ++hh) acc[hh] = 0.f;
        #pragma unroll 4
        for (int d4 = 0; d4 < DIN / 4; ++d4) {
            float4 kd = krow4[d4];
            const float* wrow = wk + 4 * d4 * H_ + h0;
            #pragma unroll
            for (int hh = 0; hh < HT; ++hh) acc[hh] = fmaf(kd.x, wrow[hh], acc[hh]);
            #pragma unroll
            for (int hh = 0; hh < HT; ++hh) acc[hh] = fmaf(kd.y, wrow[H_ + hh], acc[hh]);
            #pragma unroll
            for (int hh = 0; hh < HT; ++hh) acc[hh] = fmaf(kd.z, wrow[2 * H_ + hh], acc[hh]);
            #pragma unroll
            for (int hh = 0; hh < HT; ++hh) acc[hh] = fmaf(kd.w, wrow[3 * H_ + hh], acc[hh]);
        }
        #pragma unroll
        for (int hh = 0; hh < HT; ++hh)
            EkT[(b * H_ + h0 + hh) * TK + t] = fast_exp2(acc[hh] * SCALE);
    } else {
        // ---- Q-projection -> exp, packed 4 rows per float4, [b][g][h] ----
        int i = bx - 512;                // 0..511
        int b = i >> 5;                  // TQ/QT == 32 groups
        int g = i & 31;
        const float* qbase = queries + (size_t)(b * TQ + 4 * g) * DIN;  // uniform
        float a0 = 0.f, a1 = 0.f, a2 = 0.f, a3 = 0.f;
        #pragma unroll
        for (int d = 0; d < DIN; ++d) {
            float ww = wq[d * H_ + t];               // coalesced, L2-hot
            a0 = fmaf(qbase[d],           ww, a0);   // uniform -> scalar loads
            a1 = fmaf(qbase[DIN + d],     ww, a1);
            a2 = fmaf(qbase[2 * DIN + d], ww, a2);
            a3 = fmaf(qbase[3 * DIN + d], ww, a3);
        }
        EqW[(size_t)(b * 32 + g) * H_ + t] =
            make_float4(fast_exp2(a0 * SCALE), fast_exp2(a1 * SCALE),
                        fast_exp2(a2 * SCALE), fast_exp2(a3 * SCALE));
    }
}

__device__ inline float waveMax(float v) {
    #pragma unroll
    for (int off = 32; off > 0; off >>= 1) v = fmaxf(v, __shfl_xor(v, off, 64));
    return v;
}
__device__ inline float waveSum(float v) {
    #pragma unroll
    for (int off = 32; off > 0; off >>= 1) v += __shfl_xor(v, off, 64);
    return v;
}

// ---------------- Kernel C: scores(4 rows) + softmax + attn@V ----------------
// grid = B*(TQ/QT) = 512 blocks, 512 threads.
// Phase 1 hot loop: kv = global float4 (VMEM); Eq rows + wv_h are WAVE-UNIFORM,
// indexed by readfirstlane-derived h -> s_load (SMEM pipe, SGPR operands).
// Zero LDS and zero broadcast latency inside the loop.
__global__ __launch_bounds__(512, 4) void attn_kernel(
    const float4* __restrict__ EqW, const float* __restrict__ EkT,
    const float* __restrict__ values, const int* __restrict__ valid_lens,
    const float* __restrict__ wv, float* __restrict__ out)
{
    __shared__ float scoreP[NW][QT][TK];   // 32 KB partials of wv*r; [0] reused ph3
    __shared__ float attnT[TK][QT];        // k-major, float4-readable per k

    // XCD swizzle: 2 batches per XCD slot -> ~1 MB hot set per XCD L2.
    int bx  = blockIdx.x;
    int xcd = bx & 7;
    int i   = bx >> 3;                     // 0..63
    int b   = xcd + 8 * (i & 1);
    int g   = i >> 1;                      // q-group 0..31; q0 = 4g
    int q0  = g * QT;
    int t   = threadIdx.x;                 // 0..511
    int w   = t >> 6, l = t & 63;
    int vl  = valid_lens[b];

    // ---- phase 1: wave w covers h in [32w,32w+32); lane l covers k=4l..4l+3 ----
    {
        const float4* eqb = EqW + (size_t)(b * 32 + g) * H_;   // block-uniform
        const float4* ek4 = (const float4*)(EkT + (size_t)b * H_ * TK);
        int h0 = __builtin_amdgcn_readfirstlane(w) * (H_ / NW); // SGPR -> uniform idx
        float4 s0 = {0,0,0,0}, s1 = {0,0,0,0}, s2 = {0,0,0,0}, s3 = {0,0,0,0};

        auto body = [&](int h, float4 kv) {
            float4 eq  = eqb[h];           // uniform -> s_load_dwordx4
            float  wvh = wv[h];            // uniform -> s_load_dword
            float r;
            r = fast_rcp(fmaf(eq.x, kv.x, 1.f)); s0.x = fmaf(wvh, r, s0.x);
            r = fast_rcp(fmaf(eq.x, kv.y, 1.f)); s0.y = fmaf(wvh, r, s0.y);
            r = fast_rcp(fmaf(eq.x, kv.z, 1.f)); s0.z = fmaf(wvh, r, s0.z);
            r = fast_rcp(fmaf(eq.x, kv.w, 1.f)); s0.w = fmaf(wvh, r, s0.w);
            r = fast_rcp(fmaf(eq.y, kv.x, 1.f)); s1.x = fmaf(wvh, r, s1.x);
            r = fast_rcp(fmaf(eq.y, kv.y, 1.f)); s1.y = fmaf(wvh, r, s1.y);
            r = fast_rcp(fmaf(eq.y, kv.z, 1.f)); s1.z = fmaf(wvh, r, s1.z);
            r = fast_rcp(fmaf(eq.y, kv.w, 1.f)); s1.w = fmaf(wvh, r, s1.w);
            r = fast_rcp(fmaf(eq.z, kv.x, 1.f)); s2.x = fmaf(wvh, r, s2.x);
            r = fast_rcp(fmaf(eq.z, kv.y, 1.f)); s2.y = fmaf(wvh, r, s2.y);
            r = fast_rcp(fmaf(eq.z, kv.z, 1.f)); s2.z = fmaf(wvh, r, s2.z);
            r = fast_rcp(fmaf(eq.z, kv.w, 1.f)); s2.w = fmaf(wvh, r, s2.w);
            r = fast_rcp(fmaf(eq.w, kv.x, 1.f)); s3.x = fmaf(wvh, r, s3.x);
            r = fast_rcp(fmaf(eq.w, kv.y, 1.f)); s3.y = fmaf(wvh, r, s3.y);
            r = fast_rcp(fmaf(eq.w, kv.z, 1.f)); s3.z = fmaf(wvh, r, s3.z);
            r = fast_rcp(fmaf(eq.w, kv.w, 1.f)); s3.w = fmaf(wvh, r, s3.w);
        };

        float4 kv = ek4[(size_t)h0 * (TK / 4) + l];      // prime the pipe
        #pragma unroll 2
        for (int hh = 0; hh < H_ / NW - 1; ++hh) {
            float4 kvn = ek4[(size_t)(h0 + hh + 1) * (TK / 4) + l];  // prefetch next
            body(h0 + hh, kv);
            kv = kvn;
        }
        body(h0 + H_ / NW - 1, kv);                      // peeled last iteration

        ((float4*)&scoreP[w][0][0])[l] = s0;             // b128 stores
        ((float4*)&scoreP[w][1][0])[l] = s1;
        ((float4*)&scoreP[w][2][0])[l] = s2;
        ((float4*)&scoreP[w][3][0])[l] = s3;
    }
    __syncthreads();

    // ---- phase 2: wave r (r<QT) softmaxes row q0+r; lane covers k=4l..4l+3 ----
    if (t < 64 * QT) {
        int r = w;
        // W = sum_h wv_h; score = W - 2*sum(wv*r)
        float W = waveSum(wv[l] + wv[l + 64] + wv[l + 128] + wv[l + 192]);
        float4 v = {0, 0, 0, 0};
        #pragma unroll
        for (int s = 0; s < NW; ++s) {
            float4 ps = ((const float4*)&scoreP[s][r][0])[l];
            v.x += ps.x; v.y += ps.y; v.z += ps.z; v.w += ps.w;
        }
        int k0 = 4 * l;
        v.x = (k0     < vl) ? fmaf(-2.f, v.x, W) : NEG;
        v.y = (k0 + 1 < vl) ? fmaf(-2.f, v.y, W) : NEG;
        v.z = (k0 + 2 < vl) ? fmaf(-2.f, v.z, W) : NEG;
        v.w = (k0 + 3 < vl) ? fmaf(-2.f, v.w, W) : NEG;
        float m  = waveMax(fmaxf(fmaxf(v.x, v.y), fmaxf(v.z, v.w)));
        // vl>0: masked p underflows to exactly 0 (matches ref). vl==0: uniform.
        float p0 = fast_exp2((v.x - m) * LOG2E);
        float p1 = fast_exp2((v.y - m) * LOG2E);
        float p2 = fast_exp2((v.z - m) * LOG2E);
        float p3 = fast_exp2((v.w - m) * LOG2E);
        float dr = fast_rcp(waveSum(p0 + p1 + p2 + p3));
        attnT[k0    ][r] = p0 * dr;
        attnT[k0 + 1][r] = p1 * dr;
        attnT[k0 + 2][r] = p2 * dr;
        attnT[k0 + 3][r] = p3 * dr;
    }
    __syncthreads();

    // ---- phase 3: half-block splits k-range, clipped to vl (weights for k>=vl are 0) ----
    {
        int half = t >> 8, v = t & 255;
        int kLim = (vl == 0) ? TK : vl;        // vl==0: uniform weights over all k
        int kBeg = half * (TK / 2);
        int kEnd = min(kBeg + TK / 2, kLim);   // half1 empty when kLim<=128
        const float*  vcol = values + (size_t)b * TK * DV + v;
        const float4* at4  = (const float4*)attnT;
        float o0 = 0.f, o1 = 0.f, o2 = 0.f, o3 = 0.f;
        #pragma unroll 4
        for (int k = kBeg; k < kEnd; ++k) {
            float  vv = vcol[k * DV];          // coalesced over v
            float4 a  = at4[k];                // broadcast b128
            o0 = fmaf(a.x, vv, o0);
            o1 = fmaf(a.y, vv, o1);
            o2 = fmaf(a.z, vv, o2);
            o3 = fmaf(a.w, vv, o3);
        }
        if (half == 1) {                       // stash partials (reuse scoreP[0])
            scoreP[0][0][v] = o0;
            scoreP[0][1][v] = o1;
            scoreP[0][2][v] = o2;
            scoreP[0][3][v] = o3;
        }
        __syncthreads();
        if (half == 0) {
            float* orow = out + (size_t)(b * TQ + q0) * DV + v;
            orow[0]      = o0 + scoreP[0][0][v];
            orow[DV]     = o1 + scoreP[0][1][v];
            orow[2 * DV] = o2 + scoreP[0][2][v];
            orow[3 * DV] = o3 + scoreP[0][3][v];
        }
    }
}

extern "C" void kernel_launch(void* const* d_in, const int* in_sizes, int n_in,
                              void* d_out, int out_size, void* d_ws, size_t ws_size,
                              hipStream_t stream) {
    const float* queries    = (const float*)d_in[0];
    const float* keys       = (const float*)d_in[1];
    const float* values     = (const float*)d_in[2];
    const int*   valid_lens = (const int*)  d_in[3];
    const float* wq         = (const float*)d_in[4];
    const float* wk         = (const float*)d_in[5];
    const float* wv         = (const float*)d_in[6];
    float* out = (float*)d_out;

    float*  EkT = (float*)d_ws;                          // [B,H,TK]   = 4 MiB
    float4* EqW = (float4*)(EkT + (size_t)B_ * H_ * TK); // [B,32,H]x4 = 2 MiB

    proj_kernel<<<1024, 256, 0, stream>>>(keys, wk, queries, wq, EkT, EqW, valid_lens);
    attn_kernel<<<B_ * (TQ / QT), 512, 0, stream>>>(EqW, EkT, values,
                                                    valid_lens, wv, out);
}

// Round 13
// 96.097 us; speedup vs baseline: 1.2065x; 1.0190x over previous
//
#include <hip/hip_runtime.h>

#define B_  16
#define TQ  128
#define TK  256
#define DIN 64
#define H_  256
#define DV  256
#define HT  8          // h-cols per proj_k block
#define QT  4          // q-rows per attn block
#define NW  8          // waves per attn block (512 threads)
#define NEG -1000000.0f

// tanh(x) = 1 - 2*rcp(1 + e^{2x});  e^{2x} = exp2(SCALE*x), SCALE = 2*log2(e).
// Factorized: e^{2(q+k)} = Eq*Ek, both precomputed -> hot loop has NO exp, NO LDS.
// Reciprocals batched 2-way: 1/a = b*rcp(ab), 1/b = a*rcp(ab) -> HALF the v_rcp
// (trans pipe was the binding resource: 16 rcp x 8cyc = 128 cyc/iter vs 64 VALU).
#define SCALE  2.8853900817779268f
#define LOG2E  1.4426950408889634f

typedef float v2f __attribute__((ext_vector_type(2)));

__device__ inline float fast_exp2(float x) { return __builtin_amdgcn_exp2f(x); }
__device__ inline float fast_rcp(float x)  { return __builtin_amdgcn_rcpf(x); }
__device__ inline v2f v2fma(v2f a, v2f b, v2f c) {      // -> v_pk_fma_f32
    return __builtin_elementwise_fma(a, b, c);
}

// ---------------- Kernel B (fused producers) ----------------
// blocks 0..511:    EkT[b,h,k] = exp2(SCALE * sum_d keys[b,k,d]*wk[d,h])   (t = k)
// blocks 512..1023: EqW[b,g,h] = float4 of exp2(SCALE * qproj) for rows 4g..4g+3 (t = h)
__global__ __launch_bounds__(256) void proj_kernel(
    const float* __restrict__ keys, const float* __restrict__ wk,
    const float* __restrict__ queries, const float* __restrict__ wq,
    float* __restrict__ EkT, float4* __restrict__ EqW,
    const int* __restrict__ valid_lens)
{
    int bx = blockIdx.x;
    int t  = threadIdx.x;
    if (bx < 512) {
        // ---- K-projection -> exp, transposed [b][h][k] ----
        int b  = bx >> 5;                // H_/HT == 32
        int h0 = (bx & 31) * HT;
        int vlC = (valid_lens[b] + 63) & ~63;
        if (t >= vlC) return;            // wave-uniform exit; skipped entries stay
                                         // poisoned (finite) and are masked later
        const float4* krow4 = (const float4*)(keys + (size_t)(b * TK + t) * DIN);
        float acc[HT];
        #pragma unroll
        for (int hh = 0; hh < HT; ++hh) acc[hh] = 0.f;
        #pragma unroll 4
        for (int d4 = 0; d4 < DIN / 4; ++d4) {
            float4 kd = krow4[d4];
            const float* wrow = wk + 4 * d4 * H_ + h0;
            #pragma unroll
            for (int hh = 0; hh < HT; ++hh) acc[hh] = fmaf(kd.x, wrow[hh], acc[hh]);
            #pragma unroll
            for (int hh = 0; hh < HT; ++hh) acc[hh] = fmaf(kd.y, wrow[H_ + hh], acc[hh]);
            #pragma unroll
            for (int hh = 0; hh < HT; ++hh) acc[hh] = fmaf(kd.z, wrow[2 * H_ + hh], acc[hh]);
            #pragma unroll
            for (int hh = 0; hh < HT; ++hh) acc[hh] = fmaf(kd.w, wrow[3 * H_ + hh], acc[hh]);
        }
        #pragma unroll
        for (int hh = 0; hh < HT; ++hh)
            EkT[(b * H_ + h0 + hh) * TK + t] = fast_exp2(acc[hh] * SCALE);
    } else {
        // ---- Q-projection -> exp, packed 4 rows per float4, [b][g][h] ----
        int i = bx - 512;                // 0..511
        int b = i >> 5;                  // TQ/QT == 32 groups
        int g = i & 31;
        const float* qbase = queries + (size_t)(b * TQ + 4 * g) * DIN;  // uniform
        float a0 = 0.f, a1 = 0.f, a2 = 0.f, a3 = 0.f;
        #pragma unroll
        for (int d = 0; d < DIN; ++d) {
            float ww = wq[d * H_ + t];               // coalesced, L2-hot
            a0 = fmaf(qbase[d],           ww, a0);   // uniform -> scalar loads
            a1 = fmaf(qbase[DIN + d],     ww, a1);
            a2 = fmaf(qbase[2 * DIN + d], ww, a2);
            a3 = fmaf(qbase[3 * DIN + d], ww, a3);
        }
        EqW[(size_t)(b * 32 + g) * H_ + t] =
            make_float4(fast_exp2(a0 * SCALE), fast_exp2(a1 * SCALE),
                        fast_exp2(a2 * SCALE), fast_exp2(a3 * SCALE));
    }
}

__device__ inline float waveMax(float v) {
    #pragma unroll
    for (int off = 32; off > 0; off >>= 1) v = fmaxf(v, __shfl_xor(v, off, 64));
    return v;
}
__device__ inline float waveSum(float v) {
    #pragma unroll
    for (int off = 32; off > 0; off >>= 1) v += __shfl_xor(v, off, 64);
    return v;
}

// ---------------- Kernel C: scores(4 rows) + softmax + attn@V ----------------
// grid = B*(TQ/QT) = 512 blocks, 512 threads.
// Phase 1 hot loop: kv = global float4 (VMEM, depth-2 prefetch); Eq rows + wv_h are
// wave-uniform -> s_load (SMEM pipe). Per k-pair: pk_fma(d) + mul(pairprod) + rcp +
// pk_mul(recover) + pk_fma(acc): trans 64 cyc/iter, VALU ~64 cyc/iter -> balanced.
__global__ __launch_bounds__(512, 4) void attn_kernel(
    const float4* __restrict__ EqW, const float* __restrict__ EkT,
    const float* __restrict__ values, const int* __restrict__ valid_lens,
    const float* __restrict__ wv, float* __restrict__ out)
{
    __shared__ float scoreP[NW][QT][TK];   // 32 KB partials of wv*r; [0] reused ph3
    __shared__ float attnT[TK][QT];        // k-major, float4-readable per k

    // XCD swizzle: 2 batches per XCD slot -> ~1 MB hot set per XCD L2.
    int bx  = blockIdx.x;
    int xcd = bx & 7;
    int i   = bx >> 3;                     // 0..63
    int b   = xcd + 8 * (i & 1);
    int g   = i >> 1;                      // q-group 0..31; q0 = 4g
    int q0  = g * QT;
    int t   = threadIdx.x;                 // 0..511
    int w   = t >> 6, l = t & 63;
    int vl  = valid_lens[b];

    // ---- phase 1: wave w covers h in [32w,32w+32); lane l covers k=4l..4l+3 ----
    {
        const float4* eqb = EqW + (size_t)(b * 32 + g) * H_;   // block-uniform
        const float4* ek4 = (const float4*)(EkT + (size_t)b * H_ * TK);
        int h0 = __builtin_amdgcn_readfirstlane(w) * (H_ / NW); // SGPR -> uniform idx
        // per row: two v2f accumulators (k pair xy, k pair zw)
        v2f sA0={0,0}, sA1={0,0}, sB0={0,0}, sB1={0,0};
        v2f sC0={0,0}, sC1={0,0}, sD0={0,0}, sD1={0,0};
        const v2f one2 = {1.f, 1.f};

        auto row = [&](float eq, v2f kxy, v2f kzw, v2f w2, v2f& sp0, v2f& sp1) {
            v2f e2 = {eq, eq};
            v2f d0 = v2fma(e2, kxy, one2);             // v_pk_fma_f32
            v2f d1 = v2fma(e2, kzw, one2);
            float rp0 = fast_rcp(d0.x * d0.y);         // 1 v_rcp per 2 elems
            float rp1 = fast_rcp(d1.x * d1.y);
            v2f r0 = (v2f){d0.y, d0.x} * (v2f){rp0, rp0};   // v_pk_mul_f32
            v2f r1 = (v2f){d1.y, d1.x} * (v2f){rp1, rp1};
            sp0 = v2fma(w2, r0, sp0);                  // v_pk_fma_f32
            sp1 = v2fma(w2, r1, sp1);
        };

        auto body = [&](int h, float4 kv) {
            float4 eq  = eqb[h];                       // uniform -> s_load_dwordx4
            float  wvh = wv[h];                        // uniform -> s_load_dword
            v2f w2  = {wvh, wvh};
            v2f kxy = {kv.x, kv.y};
            v2f kzw = {kv.z, kv.w};
            row(eq.x, kxy, kzw, w2, sA0, sA1);
            row(eq.y, kxy, kzw, w2, sB0, sB1);
            row(eq.z, kxy, kzw, w2, sC0, sC1);
            row(eq.w, kxy, kzw, w2, sD0, sD1);
        };

        // depth-2 prefetch: covers ~200-cyc L2 latency over ~64-cyc iterations
        float4 kv0 = ek4[(size_t)h0 * (TK / 4) + l];
        float4 kv1 = ek4[(size_t)(h0 + 1) * (TK / 4) + l];
        #pragma unroll 2
        for (int hh = 0; hh < H_ / NW - 2; ++hh) {
            float4 kvn = ek4[(size_t)(h0 + hh + 2) * (TK / 4) + l];
            body(h0 + hh, kv0);
            kv0 = kv1; kv1 = kvn;
        }
        body(h0 + H_ / NW - 2, kv0);                   // peeled tail
        body(h0 + H_ / NW - 1, kv1);

        ((float4*)&scoreP[w][0][0])[l] = make_float4(sA0.x, sA0.y, sA1.x, sA1.y);
        ((float4*)&scoreP[w][1][0])[l] = make_float4(sB0.x, sB0.y, sB1.x, sB1.y);
        ((float4*)&scoreP[w][2][0])[l] = make_float4(sC0.x, sC0.y, sC1.x, sC1.y);
        ((float4*)&scoreP[w][3][0])[l] = make_float4(sD0.x, sD0.y, sD1.x, sD1.y);
    }
    __syncthreads();

    // ---- phase 2: wave r (r<QT) softmaxes row q0+r; lane covers k=4l..4l+3 ----
    if (t < 64 * QT) {
        int r = w;
        // W = sum_h wv_h; score = W - 2*sum(wv*r)
        float W = waveSum(wv[l] + wv[l + 64] + wv[l + 128] + wv[l + 192]);
        float4 v = {0, 0, 0, 0};
        #pragma unroll
        for (int s = 0; s < NW; ++s) {
            float4 ps = ((const float4*)&scoreP[s][r][0])[l];
            v.x += ps.x; v.y += ps.y; v.z += ps.z; v.w += ps.w;
        }
        int k0 = 4 * l;
        v.x = (k0     < vl) ? fmaf(-2.f, v.x, W) : NEG;
        v.y = (k0 + 1 < vl) ? fmaf(-2.f, v.y, W) : NEG;
        v.z = (k0 + 2 < vl) ? fmaf(-2.f, v.z, W) : NEG;
        v.w = (k0 + 3 < vl) ? fmaf(-2.f, v.w, W) : NEG;
        float m  = waveMax(fmaxf(fmaxf(v.x, v.y), fmaxf(v.z, v.w)));
        // vl>0: masked p underflows to exactly 0 (matches ref). vl==0: uniform.
        float p0 = fast_exp2((v.x - m) * LOG2E);
        float p1 = fast_exp2((v.y - m) * LOG2E);
        float p2 = fast_exp2((v.z - m) * LOG2E);
        float p3 = fast_exp2((v.w - m) * LOG2E);
        float dr = fast_rcp(waveSum(p0 + p1 + p2 + p3));
        attnT[k0    ][r] = p0 * dr;
        attnT[k0 + 1][r] = p1 * dr;
        attnT[k0 + 2][r] = p2 * dr;
        attnT[k0 + 3][r] = p3 * dr;
    }
    __syncthreads();

    // ---- phase 3: half-block splits k-range, clipped to vl (weights for k>=vl are 0) ----
    {
        int half = t >> 8, v = t & 255;
        int kLim = (vl == 0) ? TK : vl;        // vl==0: uniform weights over all k
        int kBeg = half * (TK / 2);
        int kEnd = min(kBeg + TK / 2, kLim);   // half1 empty when kLim<=128
        const float*  vcol = values + (size_t)b * TK * DV + v;
        const float4* at4  = (const float4*)attnT;
        float o0 = 0.f, o1 = 0.f, o2 = 0.f, o3 = 0.f;
        #pragma unroll 4
        for (int k = kBeg; k < kEnd; ++k) {
            float  vv = vcol[k * DV];          // coalesced over v
            float4 a  = at4[k];                // broadcast b128
            o0 = fmaf(a.x, vv, o0);
            o1 = fmaf(a.y, vv, o1);
            o2 = fmaf(a.z, vv, o2);
            o3 = fmaf(a.w, vv, o3);
        }
        if (half == 1) {                       // stash partials (reuse scoreP[0])
            scoreP[0][0][v] = o0;
            scoreP[0][1][v] = o1;
            scoreP[0][2][v] = o2;
            scoreP[0][3][v] = o3;
        }
        __syncthreads();
        if (half == 0) {
            float* orow = out + (size_t)(b * TQ + q0) * DV + v;
            orow[0]      = o0 + scoreP[0][0][v];
            orow[DV]     = o1 + scoreP[0][1][v];
            orow[2 * DV] = o2 + scoreP[0][2][v];
            orow[3 * DV] = o3 + scoreP[0][3][v];
        }
    }
}

extern "C" void kernel_launch(void* const* d_in, const int* in_sizes, int n_in,
                              void* d_out, int out_size, void* d_ws, size_t ws_size,
                              hipStream_t stream) {
    const float* queries    = (const float*)d_in[0];
    const float* keys       = (const float*)d_in[1];
    const float* values     = (const float*)d_in[2];
    const int*   valid_lens = (const int*)  d_in[3];
    const float* wq         = (const float*)d_in[4];
    const float* wk         = (const float*)d_in[5];
    const float* wv         = (const float*)d_in[6];
    float* out = (float*)d_out;

    float*  EkT = (float*)d_ws;                          // [B,H,TK]   = 4 MiB
    float4* EqW = (float4*)(EkT + (size_t)B_ * H_ * TK); // [B,32,H]x4 = 2 MiB

    proj_kernel<<<1024, 256, 0, stream>>>(keys, wk, queries, wq, EkT, EqW, valid_lens);
    attn_kernel<<<B_ * (TQ / QT), 512, 0, stream>>>(EqW, EkT, values,
                                                    valid_lens, wv, out);
}